// Round 6
// baseline (5365.013 us; speedup 1.0000x reference)
//
#include <hip/hip_runtime.h>
#include <hip/hip_bf16.h>

typedef __hip_bfloat16 bf16;

#define NA 100000
#define NT 300000
#define NG 2000
#define EPT 600000
#define ETG 400000

__device__ __forceinline__ float toF(bf16 x) { return __bfloat162float(x); }

// order-preserving encode of f32 into u32 for atomicMax-based segment max
__device__ __forceinline__ unsigned encf(float f) {
    unsigned u = __float_as_uint(f);
    return (u & 0x80000000u) ? ~u : (u | 0x80000000u);
}
__device__ __forceinline__ float decf(unsigned e) {
    return __uint_as_float((e & 0x80000000u) ? (e ^ 0x80000000u) : ~e);
}

__global__ void fill_u32(unsigned* __restrict__ p, unsigned v, long n) {
    long i = (long)blockIdx.x * 256 + threadIdx.x;
    if (i < n) p[i] = v;
}

// ---------------------------------------------------------------------------
// Naive GEMM: C[n,col] = sum_k A[n,k]*B[k*N+col] + bias[col], bf16 out.
// One thread per output element. AF32: A is f32 input; else bf16 ws buffer.
// ---------------------------------------------------------------------------
template <bool AF32>
__global__ __launch_bounds__(256) void ngemm(
    const void* __restrict__ A, const float* __restrict__ B,
    const float* __restrict__ bias, bf16* __restrict__ C,
    int M, int N, int K)
{
    long i = (long)blockIdx.x * 256 + threadIdx.x;
    if (i >= (long)M * N) return;
    int n = (int)(i / N);
    int col = (int)(i - (long)n * N);
    float acc = bias[col];
    if (AF32) {
        const float* Af = (const float*)A + (size_t)n * K;
        for (int k = 0; k < K; ++k) acc += Af[k] * B[(size_t)k * N + col];
    } else {
        const bf16* Ah = (const bf16*)A + (size_t)n * K;
        for (int k = 0; k < K; ++k) acc += toF(Ah[k]) * B[(size_t)k * N + col];
    }
    C[i] = __float2bfloat16(acc);
}

// ---------------------------------------------------------------------------
// E1: one thread per (edge, head): s = sum_c leakyrelu(gl+gr)*att; atomicMax.
// ---------------------------------------------------------------------------
__global__ __launch_bounds__(256) void e1_logits(
    const bf16* __restrict__ gl, const bf16* __restrict__ gr,
    const int* __restrict__ src, const int* __restrict__ dst,
    const float* __restrict__ att, float* __restrict__ s,
    unsigned* __restrict__ menc, int E)
{
    long i = (long)blockIdx.x * 256 + threadIdx.x;
    if (i >= (long)E * 4) return;
    int e = (int)(i >> 2), h = (int)(i & 3);
    int se = src[e], de = dst[e];
    const bf16* glp = gl + (size_t)se * 256 + h * 64;
    const bf16* grp = gr + (size_t)de * 256 + h * 64;
    const float* ap = att + h * 64;
    float acc = 0.f;
    for (int c = 0; c < 64; ++c) {
        float v = toF(glp[c]) + toF(grp[c]);
        v = (v > 0.f) ? v : 0.2f * v;
        acc += v * ap[c];
    }
    s[i] = acc;
    atomicMax(&menc[de * 4 + h], encf(acc));
}

// ---------------------------------------------------------------------------
// E2: one thread per (edge, head): ex = exp(s - m[dst]); den += ex.
// ---------------------------------------------------------------------------
__global__ __launch_bounds__(256) void e2_softmax(
    const int* __restrict__ dst, float* __restrict__ s,
    const unsigned* __restrict__ menc, float* __restrict__ den, int E)
{
    long i = (long)blockIdx.x * 256 + threadIdx.x;
    if (i >= (long)E * 4) return;
    int e = (int)(i >> 2), h = (int)(i & 3);
    int de = dst[e];
    float ex = expf(s[i] - decf(menc[de * 4 + h]));
    s[i] = ex;
    atomicAdd(&den[de * 4 + h], ex);
}

// ---------------------------------------------------------------------------
// E3: one thread per (edge, channel): hsum[dst,c] += sum_h alpha_h*gl[src,h,c].
// ---------------------------------------------------------------------------
__global__ __launch_bounds__(256) void e3_aggregate(
    const bf16* __restrict__ gl, const int* __restrict__ src,
    const int* __restrict__ dst, const float* __restrict__ s,
    const float* __restrict__ den, float* __restrict__ hsum, int E)
{
    long i = (long)blockIdx.x * 256 + threadIdx.x;
    if (i >= (long)E * 64) return;
    int e = (int)(i >> 6), c = (int)(i & 63);
    int se = src[e], de = dst[e];
    float acc = 0.f;
    for (int h = 0; h < 4; ++h) {
        float a = s[(size_t)e * 4 + h] / (den[de * 4 + h] + 1e-16f);
        acc += a * toF(gl[(size_t)se * 256 + h * 64 + c]);
    }
    atomicAdd(&hsum[(size_t)de * 64 + c], acc);
}

// ---------------------------------------------------------------------------
// h = elu(0.25*hsum + bias)  (in place, one thread per element)
// ---------------------------------------------------------------------------
__global__ __launch_bounds__(256) void nelu(
    float* __restrict__ hsum, const float* __restrict__ bias, long n)
{
    long i = (long)blockIdx.x * 256 + threadIdx.x;
    if (i >= n) return;
    int c = (int)(i & 63);
    float v = 0.25f * hsum[i] + bias[c];
    hsum[i] = (v > 0.f) ? v : expm1f(v);
}

// ---------------------------------------------------------------------------
// y[n,j] = sum_c h[n,c]*W[c*64+j] + b[j]   (one thread per element)
// ---------------------------------------------------------------------------
__global__ __launch_bounds__(256) void nlin(
    const float* __restrict__ h, const float* __restrict__ W,
    const float* __restrict__ b, float* __restrict__ y, long total)
{
    long i = (long)blockIdx.x * 256 + threadIdx.x;
    if (i >= total) return;
    int n = (int)(i >> 6), j = (int)(i & 63);
    float acc = b[j];
    const float* hp = h + (size_t)n * 64;
    for (int c = 0; c < 64; ++c) acc += hp[c] * W[(size_t)c * 64 + j];
    y[i] = acc;
}

// ---------------------------------------------------------------------------
// norm[n] = max(sqrt(sum_j y^2), 1e-12)   (one thread per node)
// ---------------------------------------------------------------------------
__global__ __launch_bounds__(256) void nrm(
    const float* __restrict__ y, float* __restrict__ norm, int Nn)
{
    int n = blockIdx.x * 256 + threadIdx.x;
    if (n >= Nn) return;
    const float* yp = y + (size_t)n * 64;
    float ss = 0.f;
    for (int j = 0; j < 64; ++j) ss += yp[j] * yp[j];
    norm[n] = fmaxf(sqrtf(ss), 1e-12f);
}

// ---------------------------------------------------------------------------
// out[n,j] = y[n,j] / norm[n]   (f32 output — the round-6 hypothesis)
// ---------------------------------------------------------------------------
__global__ __launch_bounds__(256) void nout(
    const float* __restrict__ y, const float* __restrict__ norm,
    float* __restrict__ out, long total)
{
    long i = (long)blockIdx.x * 256 + threadIdx.x;
    if (i >= total) return;
    int n = (int)(i >> 6);
    out[i] = y[i] / norm[n];
}

// ---------------------------------------------------------------------------

static inline unsigned gridFor(long n) { return (unsigned)((n + 255) / 256); }

extern "C" void kernel_launch(void* const* d_in, const int* in_sizes, int n_in,
                              void* d_out, int out_size, void* d_ws, size_t ws_size,
                              hipStream_t stream) {
    const float* x_artist = (const float*)d_in[0];
    const float* x_track  = (const float*)d_in[1];
    const float* x_genre  = (const float*)d_in[2];
    const float* enc_Wa = (const float*)d_in[3];  const float* enc_ba = (const float*)d_in[4];
    const float* enc_Wt = (const float*)d_in[5];  const float* enc_bt = (const float*)d_in[6];
    const float* enc_Wg = (const float*)d_in[7];  const float* enc_bg = (const float*)d_in[8];
    const int* src_pt = (const int*)d_in[9];
    const int* dst_pt = (const int*)d_in[10];
    const int* src_tg = (const int*)d_in[11];
    const int* dst_tg = (const int*)d_in[12];
    // layer l=1 slices (hidden never fed back -> only last layer matters)
    const float* Wl_pt   = (const float*)d_in[13] + 64 * 256;   // (2,64,4,64)
    const float* bl_pt   = (const float*)d_in[14] + 256;        // (2,4,64)
    const float* Wr_pt   = (const float*)d_in[15] + 64 * 256;
    const float* br_pt   = (const float*)d_in[16] + 256;
    const float* att_pt  = (const float*)d_in[17] + 256;        // (2,4,64)
    const float* bias_pt = (const float*)d_in[18] + 64;         // (2,64)
    const float* Wl_tg   = (const float*)d_in[19] + 64 * 256;
    const float* bl_tg   = (const float*)d_in[20] + 256;
    const float* Wr_tg   = (const float*)d_in[21] + 64 * 256;
    const float* br_tg   = (const float*)d_in[22] + 256;
    const float* att_tg  = (const float*)d_in[23] + 256;
    const float* bias_tg = (const float*)d_in[24] + 64;
    const float* lin_track_W = (const float*)d_in[25];
    const float* lin_track_b = (const float*)d_in[26];
    const float* lin_genre_W = (const float*)d_in[27];
    const float* lin_genre_b = (const float*)d_in[28];

    float* out = (float*)d_out;

    // ---- workspace layout (aliased; peak ~277 MB, same scale as R5) ----
    char* p = (char*)d_ws;
    auto take = [&](size_t bytes) { char* q = p; p += (bytes + 255) & ~(size_t)255; return q; };
    bf16* enc_t = (bf16*)take((size_t)NT * 64 * 2);
    bf16* enc_g = (bf16*)take((size_t)NG * 64 * 2);
    bf16* enc_a = (bf16*)take((size_t)NA * 64 * 2);        // tg phase: gr_tg overlays
    char* region = take((size_t)NA * 256 * 2 + (size_t)NT * 256 * 2);   // 204.8 MB
    bf16*  gl_pt  = (bf16*)region;                                      // [0, 51.2 MB)
    bf16*  gr_pt  = (bf16*)(region + (size_t)NA * 256 * 2);             // [51.2, 204.8)
    float* hsum   = (float*)gr_pt;                                      // [51.2, 128.0) after e1
    float* ybuf   = (float*)(region + (size_t)NA * 256 * 2 + (size_t)NT * 64 * 4); // [128.0, 204.8)
    bf16*  gl_tg  = (bf16*)region;                                      // [0, 153.6) tg phase
    float* hsum_g = (float*)(region + (size_t)NT * 256 * 2);            // [153.6, +0.5 MB)
    float* ybuf_g = hsum_g + (size_t)NG * 64;                           // next 0.5 MB
    bf16*  gr_tg  = (bf16*)enc_a;                                       // NG*256 <= enc_a size
    float*    sbuf = (float*)take((size_t)EPT * 4 * 4);
    unsigned* menc = (unsigned*)take((size_t)NT * 4 * 4);
    float*    den  = (float*)take((size_t)NT * 4 * 4);
    float*    norm = (float*)take((size_t)NT * 4);

    dim3 blk(256);

    // ---- encoders (f32 inputs -> bf16 ws) ----
    ngemm<true><<<gridFor((long)NA * 64), blk, 0, stream>>>(x_artist, enc_Wa, enc_ba, enc_a, NA, 64, 64);
    ngemm<true><<<gridFor((long)NT * 64), blk, 0, stream>>>(x_track,  enc_Wt, enc_bt, enc_t, NT, 64, 96);
    ngemm<true><<<gridFor((long)NG * 64), blk, 0, stream>>>(x_genre,  enc_Wg, enc_bg, enc_g, NG, 64, 32);

    // ================= performed: artist -> track =================
    ngemm<false><<<gridFor((long)NA * 256), blk, 0, stream>>>(enc_a, Wl_pt, bl_pt, gl_pt, NA, 256, 64);
    ngemm<false><<<gridFor((long)NT * 256), blk, 0, stream>>>(enc_t, Wr_pt, br_pt, gr_pt, NT, 256, 64);

    fill_u32<<<gridFor((long)NT * 4), blk, 0, stream>>>(menc, 0x007FFFFFu, (long)NT * 4);  // enc(-inf)
    fill_u32<<<gridFor((long)NT * 4), blk, 0, stream>>>((unsigned*)den, 0u, (long)NT * 4);

    e1_logits<<<gridFor((long)EPT * 4), blk, 0, stream>>>(gl_pt, gr_pt, src_pt, dst_pt, att_pt, sbuf, menc, EPT);
    e2_softmax<<<gridFor((long)EPT * 4), blk, 0, stream>>>(dst_pt, sbuf, menc, den, EPT);
    // gr_pt dead from here; hsum overlays it
    fill_u32<<<gridFor((long)NT * 64), blk, 0, stream>>>((unsigned*)hsum, 0u, (long)NT * 64);
    e3_aggregate<<<gridFor((long)EPT * 64), blk, 0, stream>>>(gl_pt, src_pt, dst_pt, sbuf, den, hsum, EPT);

    nelu<<<gridFor((long)NT * 64), blk, 0, stream>>>(hsum, bias_pt, (long)NT * 64);
    nlin<<<gridFor((long)NT * 64), blk, 0, stream>>>(hsum, lin_track_W, lin_track_b, ybuf, (long)NT * 64);
    nrm <<<gridFor(NT), blk, 0, stream>>>(ybuf, norm, NT);
    nout<<<gridFor((long)NT * 64), blk, 0, stream>>>(ybuf, norm, out, (long)NT * 64);

    // ================= has_genre: track -> genre =================
    ngemm<false><<<gridFor((long)NT * 256), blk, 0, stream>>>(enc_t, Wl_tg, bl_tg, gl_tg, NT, 256, 64);
    ngemm<false><<<gridFor((long)NG * 256), blk, 0, stream>>>(enc_g, Wr_tg, br_tg, gr_tg, NG, 256, 64);

    fill_u32<<<gridFor((long)NG * 4), blk, 0, stream>>>(menc, 0x007FFFFFu, (long)NG * 4);
    fill_u32<<<gridFor((long)NG * 4), blk, 0, stream>>>((unsigned*)den, 0u, (long)NG * 4);
    fill_u32<<<gridFor((long)NG * 64), blk, 0, stream>>>((unsigned*)hsum_g, 0u, (long)NG * 64);

    e1_logits<<<gridFor((long)ETG * 4), blk, 0, stream>>>(gl_tg, gr_tg, src_tg, dst_tg, att_tg, sbuf, menc, ETG);
    e2_softmax<<<gridFor((long)ETG * 4), blk, 0, stream>>>(dst_tg, sbuf, menc, den, ETG);
    e3_aggregate<<<gridFor((long)ETG * 64), blk, 0, stream>>>(gl_tg, src_tg, dst_tg, sbuf, den, hsum_g, ETG);

    nelu<<<gridFor((long)NG * 64), blk, 0, stream>>>(hsum_g, bias_tg, (long)NG * 64);
    nlin<<<gridFor((long)NG * 64), blk, 0, stream>>>(hsum_g, lin_genre_W, lin_genre_b, ybuf_g, (long)NG * 64);
    nrm <<<gridFor(NG), blk, 0, stream>>>(ybuf_g, norm, NG);
    nout<<<gridFor((long)NG * 64), blk, 0, stream>>>(ybuf_g, norm, out + (size_t)NT * 64, (long)NG * 64);
}